// Round 13
// baseline (249.325 us; speedup 1.0000x reference)
//
#include <hip/hip_runtime.h>

#define NN 100000
#define NE 800000
#define IND 64
#define HID 96
#define NL 3
#define NC 512
#define BN_EPS 1e-5f

#define NBE ((NN + 127) / 128)       // 782 embed blocks
#define NBP (NL * 9)                 // 27 layer-prep blocks
#define NBF ((NE + 4095) / 4096)     // 196 pass1 partition blocks
#define NBK2 196                     // buckets (dst >> 9)
#define BCAP 4864                    // bucket capacity (mean 4096 + 12 sigma)

typedef __attribute__((ext_vector_type(8))) short bf16x8;
typedef __attribute__((ext_vector_type(4))) float f32x4;

static __device__ __forceinline__ float b2f(ushort u) {
    union { uint i; float f; } v; v.i = ((uint)u) << 16; return v.f;
}
static __device__ __forceinline__ ushort f2b(float f) {
    union { float f; uint i; } v; v.f = f;
    uint r = v.i + 0x7FFFu + ((v.i >> 16) & 1u);
    return (ushort)(r >> 16);
}
static __device__ __forceinline__ uint pack2(float a, float b) {
    return (uint)f2b(a) | ((uint)f2b(b) << 16);
}

// frag-order conversion: t-th fragment of [K][96] fp32 (A rows 0..95, B rows 96..191)
static __device__ __forceinline__ void prep_one(const float* srcA, const float* srcB,
                                                ushort* dst, int t) {
    int lane = t & 63;
    int ct = (t >> 6) % 6;
    int kt = t / (6 * 64);
    int k0 = kt * 32 + (lane >> 4) * 8;
    int col = ct * 16 + (lane & 15);
    ushort tmp[8];
#pragma unroll
    for (int j = 0; j < 8; ++j) {
        int k = k0 + j;
        const float* src = (srcB == nullptr || k < 96) ? srcA : srcB;
        int kk = (srcB == nullptr || k < 96) ? k : k - 96;
        tmp[j] = f2b(src[kk * HID + col]);
    }
    uint* od = (uint*)(dst + (size_t)t * 8);
    od[0] = (uint)tmp[0] | ((uint)tmp[1] << 16);
    od[1] = (uint)tmp[2] | ((uint)tmp[3] << 16);
    od[2] = (uint)tmp[4] | ((uint)tmp[5] << 16);
    od[3] = (uint)tmp[6] | ((uint)tmp[7] << 16);
}

// ---- fused front: embed (MFMA, LDS-staged x) + layer-weight prep (+stats zero)
//      + edge bucket-partition ----
__global__ __launch_bounds__(256) void k_front(const float* __restrict__ x,
        const float* __restrict__ W_emb, const float* __restrict__ bias,
        ushort* __restrict__ h,
        const float* __restrict__ conv_wl, const float* __restrict__ conv_wr,
        ushort* __restrict__ Bfl, float* __restrict__ stats,
        const int* __restrict__ ei, int* __restrict__ gcur,
        uint* __restrict__ part) {
    __shared__ __align__(16) char smem[30720];
    const int b = blockIdx.x;
    const int tid = threadIdx.x;
    if (b >= NBE) {
        if (b < NBE + NBP) {           // ---- layer-weight prep ----
            int idx = b - NBE;
            int l = idx / 9, bb = idx % 9;
            int t = bb * 256 + tid;
            if (t < 6 * 6 * 64)
                prep_one(conv_wl + (size_t)l * 9216, conv_wr + (size_t)l * 9216,
                         Bfl + (size_t)l * 18432, t);
            if (bb == 0 && tid < 192) stats[(size_t)l * 192 + tid] = 0.f;
        } else {                        // ---- pass1: bucket partition ----
            uint* ordbuf = (uint*)smem;                      // 4096 uint
            unsigned char* sbk = (unsigned char*)(smem + 16384); // 4096
            int* lhist = (int*)(smem + 20480);               // 256
            int* lscan = (int*)(smem + 21504);               // 256
            int* lbase = (int*)(smem + 22528);               // 256
            int* lcnt2 = (int*)(smem + 23552);               // 256
            const int base_e = (b - NBE - NBP) * 4096;
            lhist[tid] = 0; lcnt2[tid] = 0;
            __syncthreads();
#pragma unroll
            for (int it = 0; it < 16; ++it) {
                int e = base_e + it * 256 + tid;
                if (e < NE) atomicAdd(&lhist[ei[NE + e] >> 9], 1);
            }
            __syncthreads();
            int v = lhist[tid];
            lscan[tid] = v;
            __syncthreads();
            for (int off = 1; off < 256; off <<= 1) {
                int t2 = (tid >= off) ? lscan[tid - off] : 0;
                __syncthreads();
                lscan[tid] += t2;
                __syncthreads();
            }
            int excl = lscan[tid] - v;
            __syncthreads();
            lscan[tid] = excl;
            if (v > 0) lbase[tid] = atomicAdd(&gcur[tid], v);
            __syncthreads();
#pragma unroll
            for (int it = 0; it < 16; ++it) {
                int e = base_e + it * 256 + tid;
                if (e < NE) {
                    int s = ei[e], d = ei[NE + e];
                    int bk = d >> 9;
                    int lofs = atomicAdd(&lcnt2[bk], 1);
                    int slot = lscan[bk] + lofs;
                    ordbuf[slot] = (uint)s | ((uint)(d & 511) << 17);
                    sbk[slot] = (unsigned char)bk;
                }
            }
            __syncthreads();
            int total = NE - base_e; if (total > 4096) total = 4096;
            for (int i = tid; i < total; i += 256) {
                int bk = sbk[i];
                part[(size_t)bk * BCAP + lbase[bk] + (i - lscan[bk])] = ordbuf[i];
            }
        }
        return;
    }
    // ---- embed role ----
    ushort* sB = (ushort*)smem;               // frag-ordered W_emb (12288 B)
    ushort* sX = (ushort*)(smem + 12288);     // [128][72] bf16 x-tile (18432 B)
    ushort* sT = (ushort*)smem;               // reused after MFMA: 128*96 bf16
    for (int i = tid; i < 768; i += 256) {
        int lane = i & 63;
        int ct = (i >> 6) % 6;
        int kt = i / (6 * 64);
        int k0 = kt * 32 + (lane >> 4) * 8;
        int col = ct * 16 + (lane & 15);
        ushort tmp[8];
#pragma unroll
        for (int j = 0; j < 8; ++j) tmp[j] = f2b(W_emb[(k0 + j) * HID + col]);
        uint4 o;
        o.x = (uint)tmp[0] | ((uint)tmp[1] << 16);
        o.y = (uint)tmp[2] | ((uint)tmp[3] << 16);
        o.z = (uint)tmp[4] | ((uint)tmp[5] << 16);
        o.w = (uint)tmp[6] | ((uint)tmp[7] << 16);
        ((uint4*)sB)[i] = o;
    }
    // coalesced x-tile stage: 128 rows x 16 float4
    for (int i = tid; i < 2048; i += 256) {
        int r = i >> 4, c4 = (i & 15) * 4;
        int g = b * 128 + r; if (g >= NN) g = NN - 1;
        float4 f = *(const float4*)&x[(size_t)g * IND + c4];
        *(uint2*)&sX[r * 72 + c4] = make_uint2(pack2(f.x, f.y), pack2(f.z, f.w));
    }
    __syncthreads();
    const int wave = tid >> 6, lane = tid & 63;
    const int rowb = wave * 32;
    const int kof = (lane >> 4) * 8;
    f32x4 acc[2][6];
#pragma unroll
    for (int t = 0; t < 2; ++t)
#pragma unroll
        for (int c = 0; c < 6; ++c) acc[t][c] = (f32x4){0.f, 0.f, 0.f, 0.f};
#pragma unroll
    for (int kt = 0; kt < 2; ++kt) {
        int kk = kt * 32 + kof;
        bf16x8 a[2];
#pragma unroll
        for (int t = 0; t < 2; ++t) {
            int rb = rowb + t * 16 + (lane & 15);
            a[t] = *(const bf16x8*)&sX[rb * 72 + kk];
        }
#pragma unroll
        for (int ct = 0; ct < 6; ++ct) {
            bf16x8 bb = *(const bf16x8*)&sB[((kt * 6 + ct) * 64 + lane) * 8];
            acc[0][ct] = __builtin_amdgcn_mfma_f32_16x16x32_bf16(a[0], bb, acc[0][ct], 0, 0, 0);
            acc[1][ct] = __builtin_amdgcn_mfma_f32_16x16x32_bf16(a[1], bb, acc[1][ct], 0, 0, 0);
        }
    }
    __syncthreads();
#pragma unroll
    for (int t = 0; t < 2; ++t)
#pragma unroll
        for (int ct = 0; ct < 6; ++ct) {
            int col = ct * 16 + (lane & 15);
            float bv = bias[col];
#pragma unroll
            for (int i = 0; i < 4; ++i) {
                int rb = rowb + t * 16 + (lane >> 4) * 4 + i;
                float v = acc[t][ct][i] + bv;
                sT[rb * HID + col] = f2b(v > 0.f ? v : 0.f);
            }
        }
    __syncthreads();
    for (int i = tid; i < 1536; i += 256) {
        int r = i / 12;
        int g = b * 128 + r;
        if (g < NN) ((uint4*)(h + (size_t)g * HID))[i % 12] = ((uint4*)sT)[i];
    }
}

// ---- fill3: self-scan bucket bases + per-bucket node hist/scan -> rp, col ----
__global__ __launch_bounds__(256) void k_fill3(const uint* __restrict__ part,
        const int* __restrict__ gcur, int* __restrict__ rp, int* __restrict__ col) {
    __shared__ int lh[512];
    __shared__ int lsc[512];
    __shared__ int pairs[256];
    __shared__ int sge[256];
    const int tid = threadIdx.x;
    const int bk = blockIdx.x;
    // bucket-base scan (all 196 totals, every block)
    int gv = (tid < NBK2) ? gcur[tid] : 0;
    sge[tid] = gv;
    lh[tid] = 0; lh[tid + 256] = 0;
    __syncthreads();
    for (int off = 1; off < 256; off <<= 1) {
        int t = (tid >= off) ? sge[tid - off] : 0;
        __syncthreads();
        sge[tid] += t;
        __syncthreads();
    }
    int incl = sge[tid];
    __syncthreads();
    sge[tid] = incl - gv;          // exclusive
    __syncthreads();
    const int base = sge[bk];
    const int cnt = gcur[bk];
    const uint* pb = part + (size_t)bk * BCAP;
    for (int e = tid; e < cnt; e += 256) atomicAdd(&lh[pb[e] >> 17], 1);
    __syncthreads();
    int p0 = lh[2 * tid], p1 = lh[2 * tid + 1];
    int ps = p0 + p1;
    pairs[tid] = ps;
    __syncthreads();
    for (int off = 1; off < 256; off <<= 1) {
        int t = (tid >= off) ? pairs[tid - off] : 0;
        __syncthreads();
        pairs[tid] += t;
        __syncthreads();
    }
    int excl = base + pairs[tid] - ps;
    lsc[2 * tid] = excl;
    lsc[2 * tid + 1] = excl + p0;
    __syncthreads();
    const int n0 = bk * 512;
    for (int i = tid; i < 512; i += 256) {
        int n = n0 + i;
        if (n < NN) rp[n] = lsc[i];
    }
    if (bk == NBK2 - 1 && tid == 0) rp[NN] = NE;
    __syncthreads();
    for (int e = tid; e < cnt; e += 256) {
        uint v = pb[e];
        int pos = atomicAdd(&lsc[v >> 17], 1);
        col[pos] = (int)(v & 0x1FFFF);
    }
}

// ---- mean aggregation: 16 lanes/node, 4-edge unroll, BN(prev)+ReLU fused ----
__global__ __launch_bounds__(256, 8) void k_agg(const ushort* __restrict__ pre,
        const int* __restrict__ rp, const int* __restrict__ col,
        const float* __restrict__ stats, const float* __restrict__ gamma,
        const float* __restrict__ beta, ushort* __restrict__ agg) {
    __shared__ float sc[96], sh[96];
    const int tid = threadIdx.x;
    if (tid < 96) {
        float scv = 1.f, shv = 0.f;
        if (stats) {
            float mean = stats[tid] * (1.f / NN);
            float var  = stats[96 + tid] * (1.f / NN) - mean * mean;
            float s = gamma[tid] * rsqrtf(var + BN_EPS);
            scv = s; shv = beta[tid] - mean * s;
        }
        sc[tid] = scv; sh[tid] = shv;
    }
    __syncthreads();
    const int lane = tid & 15;
    const int n = blockIdx.x * 16 + (tid >> 4);
    if (n >= NN) return;
    const float s0a = sc[2*lane],      h0a = sh[2*lane];
    const float s0b = sc[2*lane + 1],  h0b = sh[2*lane + 1];
    const float s1a = sc[2*lane + 32], h1a = sh[2*lane + 32];
    const float s1b = sc[2*lane + 33], h1b = sh[2*lane + 33];
    const float s2a = sc[2*lane + 64], h2a = sh[2*lane + 64];
    const float s2b = sc[2*lane + 65], h2b = sh[2*lane + 65];
    const int e0 = rp[n], e1 = rp[n + 1];
    float a0 = 0.f, a1 = 0.f, a2 = 0.f, a3 = 0.f, a4 = 0.f, a5 = 0.f;
    const uint* hb = (const uint*)pre + lane;
    int e = e0;
    for (; e + 4 <= e1; e += 4) {
        uint u[4][3];
#pragma unroll
        for (int i = 0; i < 4; ++i) {
            const uint* r = hb + (size_t)col[e + i] * 48;
            u[i][0] = r[0]; u[i][1] = r[16]; u[i][2] = r[32];
        }
#pragma unroll
        for (int i = 0; i < 4; ++i) {
            a0 += fmaxf(b2f((ushort)u[i][0])         * s0a + h0a, 0.f);
            a1 += fmaxf(b2f((ushort)(u[i][0] >> 16)) * s0b + h0b, 0.f);
            a2 += fmaxf(b2f((ushort)u[i][1])         * s1a + h1a, 0.f);
            a3 += fmaxf(b2f((ushort)(u[i][1] >> 16)) * s1b + h1b, 0.f);
            a4 += fmaxf(b2f((ushort)u[i][2])         * s2a + h2a, 0.f);
            a5 += fmaxf(b2f((ushort)(u[i][2] >> 16)) * s2b + h2b, 0.f);
        }
    }
    for (; e < e1; ++e) {
        const uint* r = hb + (size_t)col[e] * 48;
        uint u0 = r[0], u1 = r[16], u2 = r[32];
        a0 += fmaxf(b2f((ushort)u0)         * s0a + h0a, 0.f);
        a1 += fmaxf(b2f((ushort)(u0 >> 16)) * s0b + h0b, 0.f);
        a2 += fmaxf(b2f((ushort)u1)         * s1a + h1a, 0.f);
        a3 += fmaxf(b2f((ushort)(u1 >> 16)) * s1b + h1b, 0.f);
        a4 += fmaxf(b2f((ushort)u2)         * s2a + h2a, 0.f);
        a5 += fmaxf(b2f((ushort)(u2 >> 16)) * s2b + h2b, 0.f);
    }
    int d = e1 - e0; if (d < 1) d = 1;
    float inv = 1.0f / (float)d;
    uint* ar = (uint*)agg + (size_t)n * 48 + lane;
    ar[0]  = pack2(a0 * inv, a1 * inv);
    ar[16] = pack2(a2 * inv, a3 * inv);
    ar[32] = pack2(a4 * inv, a5 * inv);
}

// ---- layer GEMM: hnew = [agg | norm_prev(pre)] @ [[wl],[wr]] + bl,
//      fused BN stats; B-frags straight from global (L2-hot) ----
__global__ __launch_bounds__(256, 5) void k_gemm(const ushort* __restrict__ aggb,
        const ushort* __restrict__ pre, const ushort* __restrict__ Bf,
        const float* __restrict__ bl, ushort* __restrict__ hnew,
        float* __restrict__ stats,
        const float* __restrict__ statsP, const float* __restrict__ gammaP,
        const float* __restrict__ betaP) {
    __shared__ __align__(16) char smem[28416];
    ushort* sT = (ushort*)smem;                    // 24576 B
    float*  sredS = (float*)(smem + 24576);        // 384 floats
    float*  sredQ = (float*)(smem + 26112);        // 384 floats
    float2* sscsh = (float2*)(smem + 27648);       // 96 float2
    const int tid = threadIdx.x;
    if (tid < 96) {
        float scv = 1.f, shv = 0.f;
        if (statsP) {
            float mean = statsP[tid] * (1.f / NN);
            float var  = statsP[96 + tid] * (1.f / NN) - mean * mean;
            float s = gammaP[tid] * rsqrtf(var + BN_EPS);
            scv = s; shv = betaP[tid] - mean * s;
        }
        sscsh[tid] = make_float2(scv, shv);
    }
    __syncthreads();
    const int wave = tid >> 6, lane = tid & 63;
    const int rowb = wave * 32;
    const int row0 = blockIdx.x * 128 + rowb;
    const int kof = (lane >> 4) * 8;
    f32x4 acc[2][6];
#pragma unroll
    for (int t = 0; t < 2; ++t)
#pragma unroll
        for (int c = 0; c < 6; ++c) acc[t][c] = (f32x4){0.f, 0.f, 0.f, 0.f};
#pragma unroll
    for (int kt = 0; kt < 6; ++kt) {
        bf16x8 a[2];
#pragma unroll
        for (int t = 0; t < 2; ++t) {
            int r = row0 + t * 16 + (lane & 15);
            if (r >= NN) r = NN - 1;
            if (kt < 3) {
                int kk = kt * 32 + kof;
                a[t] = *(const bf16x8*)(aggb + (size_t)r * HID + kk);
            } else {
                int kk = (kt - 3) * 32 + kof;
                bf16x8 raw = *(const bf16x8*)(pre + (size_t)r * HID + kk);
                union { bf16x8 h; uint u[4]; } pk;
#pragma unroll
                for (int j = 0; j < 4; ++j) {
                    float2 p0 = sscsh[kk + 2*j];
                    float2 p1 = sscsh[kk + 2*j + 1];
                    float v0 = fmaxf(b2f((ushort)raw[2*j])     * p0.x + p0.y, 0.f);
                    float v1 = fmaxf(b2f((ushort)raw[2*j + 1]) * p1.x + p1.y, 0.f);
                    pk.u[j] = pack2(v0, v1);
                }
                a[t] = pk.h;
            }
        }
#pragma unroll
        for (int ct = 0; ct < 6; ++ct) {
            bf16x8 bb = *(const bf16x8*)&Bf[((kt * 6 + ct) * 64 + lane) * 8];
            acc[0][ct] = __builtin_amdgcn_mfma_f32_16x16x32_bf16(a[0], bb, acc[0][ct], 0, 0, 0);
            acc[1][ct] = __builtin_amdgcn_mfma_f32_16x16x32_bf16(a[1], bb, acc[1][ct], 0, 0, 0);
        }
    }
    float s[6], q[6];
#pragma unroll
    for (int c = 0; c < 6; ++c) { s[c] = 0.f; q[c] = 0.f; }
#pragma unroll
    for (int t = 0; t < 2; ++t)
#pragma unroll
        for (int ct = 0; ct < 6; ++ct) {
            int col = ct * 16 + (lane & 15);
            float bv = bl[col];
#pragma unroll
            for (int i = 0; i < 4; ++i) {
                int rb = rowb + t * 16 + (lane >> 4) * 4 + i;
                int g = blockIdx.x * 128 + rb;
                float v = acc[t][ct][i] + bv;
                if (g < NN) { s[ct] += v; q[ct] += v * v; }
                sT[rb * HID + col] = f2b(v);
            }
        }
#pragma unroll
    for (int c = 0; c < 6; ++c) {
        s[c] += __shfl_xor(s[c], 16); s[c] += __shfl_xor(s[c], 32);
        q[c] += __shfl_xor(q[c], 16); q[c] += __shfl_xor(q[c], 32);
    }
    if (lane < 16) {
#pragma unroll
        for (int c = 0; c < 6; ++c) {
            sredS[wave * 96 + c * 16 + lane] = s[c];
            sredQ[wave * 96 + c * 16 + lane] = q[c];
        }
    }
    __syncthreads();
    if (tid < 96) {
        float S = sredS[tid] + sredS[96 + tid] + sredS[192 + tid] + sredS[288 + tid];
        float Q = sredQ[tid] + sredQ[96 + tid] + sredQ[192 + tid] + sredQ[288 + tid];
        atomicAdd(&stats[tid], S);
        atomicAdd(&stats[96 + tid], Q);
    }
    for (int i = tid; i < 1536; i += 256) {
        int r = i / 12;
        int g = blockIdx.x * 128 + r;
        if (g < NN) ((uint4*)(hnew + (size_t)g * HID))[i % 12] = ((uint4*)sT)[i];
    }
}

// ---------------- central-node MLP head (final BN+ReLU fused) ----------------
__global__ __launch_bounds__(128) void k_mlp(const ushort* __restrict__ pre,
        const int* __restrict__ cidx, const float* __restrict__ stats,
        const float* __restrict__ gamma, const float* __restrict__ beta,
        const float* __restrict__ W1, const float* __restrict__ b1,
        const float* __restrict__ W2, const float* __restrict__ b2,
        float* __restrict__ out) {
    __shared__ float nh[96];
    __shared__ float hid[96];
    __shared__ float red[128];
    const int c = blockIdx.x;
    const int node = cidx[c];
    const int tid = threadIdx.x;
    if (tid < 96) {
        float mean = stats[tid] * (1.f / NN);
        float var  = stats[96 + tid] * (1.f / NN) - mean * mean;
        float s = gamma[tid] * rsqrtf(var + BN_EPS);
        float v = b2f(pre[(size_t)node * 96 + tid]) * s + (beta[tid] - mean * s);
        nh[tid] = fmaxf(v, 0.f);
    }
    __syncthreads();
    if (tid < 96) {
        float a = 0.f;
        for (int k = 0; k < 96; ++k) a += nh[k] * W1[k * 96 + tid];
        hid[tid] = fmaxf(a + b1[tid], 0.f);
    }
    __syncthreads();
    red[tid] = (tid < 96) ? hid[tid] * W2[tid] : 0.f;
    __syncthreads();
    for (int off = 64; off > 0; off >>= 1) {
        if (tid < off) red[tid] += red[tid + off];
        __syncthreads();
    }
    if (tid == 0) out[c] = red[0] + b2[0];
}

extern "C" void kernel_launch(void* const* d_in, const int* in_sizes, int n_in,
                              void* d_out, int out_size, void* d_ws, size_t ws_size,
                              hipStream_t stream) {
    const float* x        = (const float*)d_in[0];
    const int*   ei       = (const int*)d_in[1];
    const int*   cidx     = (const int*)d_in[3];
    const float* W_emb    = (const float*)d_in[4];
    const float* b_emb    = (const float*)d_in[5];
    const float* conv_wl  = (const float*)d_in[6];
    const float* conv_bl  = (const float*)d_in[7];
    const float* conv_wr  = (const float*)d_in[8];
    const float* bn_gamma = (const float*)d_in[9];
    const float* bn_beta  = (const float*)d_in[10];
    const float* W1       = (const float*)d_in[11];
    const float* b1       = (const float*)d_in[12];
    const float* W2       = (const float*)d_in[13];
    const float* b2       = (const float*)d_in[14];
    float* out = (float*)d_out;

    char* ws = (char*)d_ws;
    size_t off = 0;
    auto alloc = [&](size_t bytes) -> void* {
        void* p = ws + off;
        off = (off + bytes + 255) & ~(size_t)255;
        return p;
    };
    ushort* h    = (ushort*)alloc((size_t)NN * 96 * 2);
    ushort* hnew = (ushort*)alloc((size_t)NN * 96 * 2);
    ushort* agg  = (ushort*)alloc((size_t)NN * 96 * 2);
    int*   gcur  = (int*)alloc(256 * 4);
    int*   rp    = (int*)alloc((size_t)(NN + 1) * 4);
    int*   col   = (int*)alloc((size_t)NE * 4);
    uint*  part  = (uint*)alloc((size_t)NBK2 * BCAP * 4);
    float* stats = (float*)alloc((size_t)NL * 192 * 4);
    ushort* Bfl  = (ushort*)alloc((size_t)NL * 6 * 6 * 64 * 8 * 2);
    (void)ws_size; (void)in_sizes; (void)n_in; (void)out_size;

    hipMemsetAsync(gcur, 0, 256 * 4, stream);

    k_front<<<NBE + NBP + NBF, 256, 0, stream>>>(x, W_emb, b_emb, h,
        conv_wl, conv_wr, Bfl, stats, ei, gcur, part);
    k_fill3<<<NBK2, 256, 0, stream>>>(part, gcur, rp, col);

    // ping-pong: src -> dst per layer
    const ushort* src = h;
    ushort* dst = hnew;
    for (int l = 0; l < NL; ++l) {
        const float* stP = (l == 0) ? nullptr : stats + (size_t)(l - 1) * 192;
        const float* gP  = (l == 0) ? nullptr : bn_gamma + (size_t)(l - 1) * 96;
        const float* bP  = (l == 0) ? nullptr : bn_beta + (size_t)(l - 1) * 96;
        k_agg<<<(NN + 15) / 16, 256, 0, stream>>>(src, rp, col, stP, gP, bP, agg);
        k_gemm<<<(NN + 127) / 128, 256, 0, stream>>>(agg, src,
            Bfl + (size_t)l * 18432, conv_bl + (size_t)l * 96, dst,
            stats + (size_t)l * 192, stP, gP, bP);
        const ushort* t = src; src = dst; dst = (ushort*)t;
    }
    k_mlp<<<NC, 128, 0, stream>>>(src, cidx, stats + (size_t)(NL - 1) * 192,
        bn_gamma + (size_t)(NL - 1) * 96, bn_beta + (size_t)(NL - 1) * 96,
        W1, b1, W2, b2, out);
}

// Round 14
// 242.560 us; speedup vs baseline: 1.0279x; 1.0279x over previous
//
#include <hip/hip_runtime.h>

#define NN 100000
#define NE 800000
#define IND 64
#define HID 96
#define NL 3
#define NC 512
#define BN_EPS 1e-5f

#define NBE ((NN + 127) / 128)       // 782 embed blocks
#define NBP (NL * 9)                 // 27 layer-prep blocks
#define NBF ((NE + 4095) / 4096)     // 196 pass1 partition blocks
#define NBK2 196                     // buckets (dst >> 9)
#define BCAP 4864                    // bucket capacity (mean 4096 + 12 sigma)

typedef __attribute__((ext_vector_type(8))) short bf16x8;
typedef __attribute__((ext_vector_type(4))) float f32x4;

static __device__ __forceinline__ float b2f(ushort u) {
    union { uint i; float f; } v; v.i = ((uint)u) << 16; return v.f;
}
static __device__ __forceinline__ ushort f2b(float f) {
    union { float f; uint i; } v; v.f = f;
    uint r = v.i + 0x7FFFu + ((v.i >> 16) & 1u);
    return (ushort)(r >> 16);
}
static __device__ __forceinline__ uint pack2(float a, float b) {
    return (uint)f2b(a) | ((uint)f2b(b) << 16);
}

// frag-order conversion: t-th fragment of [K][96] fp32 (A rows 0..95, B rows 96..191)
static __device__ __forceinline__ void prep_one(const float* srcA, const float* srcB,
                                                ushort* dst, int t) {
    int lane = t & 63;
    int ct = (t >> 6) % 6;
    int kt = t / (6 * 64);
    int k0 = kt * 32 + (lane >> 4) * 8;
    int col = ct * 16 + (lane & 15);
    ushort tmp[8];
#pragma unroll
    for (int j = 0; j < 8; ++j) {
        int k = k0 + j;
        const float* src = (srcB == nullptr || k < 96) ? srcA : srcB;
        int kk = (srcB == nullptr || k < 96) ? k : k - 96;
        tmp[j] = f2b(src[kk * HID + col]);
    }
    uint* od = (uint*)(dst + (size_t)t * 8);
    od[0] = (uint)tmp[0] | ((uint)tmp[1] << 16);
    od[1] = (uint)tmp[2] | ((uint)tmp[3] << 16);
    od[2] = (uint)tmp[4] | ((uint)tmp[5] << 16);
    od[3] = (uint)tmp[6] | ((uint)tmp[7] << 16);
}

// ---- fused front: embed (MFMA) + layer-weight prep (+stats zero) + partition ----
__global__ __launch_bounds__(256) void k_front(const float* __restrict__ x,
        const float* __restrict__ W_emb, const float* __restrict__ bias,
        ushort* __restrict__ h,
        const float* __restrict__ conv_wl, const float* __restrict__ conv_wr,
        ushort* __restrict__ Bfl, float* __restrict__ stats,
        const int* __restrict__ ei, int* __restrict__ gcur,
        uint* __restrict__ part) {
    __shared__ __align__(16) char smem[24576];
    const int b = blockIdx.x;
    const int tid = threadIdx.x;
    if (b >= NBE) {
        if (b < NBE + NBP) {           // ---- layer-weight prep ----
            int idx = b - NBE;
            int l = idx / 9, bb = idx % 9;
            int t = bb * 256 + tid;
            if (t < 6 * 6 * 64)
                prep_one(conv_wl + (size_t)l * 9216, conv_wr + (size_t)l * 9216,
                         Bfl + (size_t)l * 18432, t);
            if (bb == 0 && tid < 192) stats[(size_t)l * 192 + tid] = 0.f;
        } else {                        // ---- pass1: bucket partition ----
            uint* ordbuf = (uint*)smem;                      // 4096 uint
            unsigned char* sbk = (unsigned char*)(smem + 16384); // 4096
            int* lhist = (int*)(smem + 20480);               // 256
            int* lscan = (int*)(smem + 21504);               // 256
            int* lbase = (int*)(smem + 22528);               // 256
            int* lcnt2 = (int*)(smem + 23552);               // 256
            const int base_e = (b - NBE - NBP) * 4096;
            lhist[tid] = 0; lcnt2[tid] = 0;
            __syncthreads();
#pragma unroll
            for (int it = 0; it < 16; ++it) {
                int e = base_e + it * 256 + tid;
                if (e < NE) atomicAdd(&lhist[ei[NE + e] >> 9], 1);
            }
            __syncthreads();
            int v = lhist[tid];
            lscan[tid] = v;
            __syncthreads();
            for (int off = 1; off < 256; off <<= 1) {
                int t2 = (tid >= off) ? lscan[tid - off] : 0;
                __syncthreads();
                lscan[tid] += t2;
                __syncthreads();
            }
            int excl = lscan[tid] - v;
            __syncthreads();
            lscan[tid] = excl;
            if (v > 0) lbase[tid] = atomicAdd(&gcur[tid], v);
            __syncthreads();
#pragma unroll
            for (int it = 0; it < 16; ++it) {
                int e = base_e + it * 256 + tid;
                if (e < NE) {
                    int s = ei[e], d = ei[NE + e];
                    int bk = d >> 9;
                    int lofs = atomicAdd(&lcnt2[bk], 1);
                    int slot = lscan[bk] + lofs;
                    ordbuf[slot] = (uint)s | ((uint)(d & 511) << 17);
                    sbk[slot] = (unsigned char)bk;
                }
            }
            __syncthreads();
            int total = NE - base_e; if (total > 4096) total = 4096;
            for (int i = tid; i < total; i += 256) {
                int bk = sbk[i];
                part[(size_t)bk * BCAP + lbase[bk] + (i - lscan[bk])] = ordbuf[i];
            }
        }
        return;
    }
    // ---- embed role ----
    ushort* sB = (ushort*)smem;          // frag-ordered W_emb (12288 B)
    ushort* sT = (ushort*)smem;          // reused after MFMA: 128*96 bf16
    for (int i = tid; i < 768; i += 256) {
        int lane = i & 63;
        int ct = (i >> 6) % 6;
        int kt = i / (6 * 64);
        int k0 = kt * 32 + (lane >> 4) * 8;
        int col = ct * 16 + (lane & 15);
        ushort tmp[8];
#pragma unroll
        for (int j = 0; j < 8; ++j) tmp[j] = f2b(W_emb[(k0 + j) * HID + col]);
        uint4 o;
        o.x = (uint)tmp[0] | ((uint)tmp[1] << 16);
        o.y = (uint)tmp[2] | ((uint)tmp[3] << 16);
        o.z = (uint)tmp[4] | ((uint)tmp[5] << 16);
        o.w = (uint)tmp[6] | ((uint)tmp[7] << 16);
        ((uint4*)sB)[i] = o;
    }
    __syncthreads();
    const int wave = tid >> 6, lane = tid & 63;
    const int rowb = wave * 32;
    const int row0 = b * 128 + rowb;
    const int kof = (lane >> 4) * 8;
    f32x4 acc[2][6];
#pragma unroll
    for (int t = 0; t < 2; ++t)
#pragma unroll
        for (int c = 0; c < 6; ++c) acc[t][c] = (f32x4){0.f, 0.f, 0.f, 0.f};
#pragma unroll
    for (int kt = 0; kt < 2; ++kt) {
        int kk = kt * 32 + kof;
        bf16x8 a[2];
#pragma unroll
        for (int t = 0; t < 2; ++t) {
            int r = row0 + t * 16 + (lane & 15);
            if (r >= NN) r = NN - 1;
            const float* src = x + (size_t)r * IND + kk;
            float4 f0 = *(const float4*)src;
            float4 f1 = *(const float4*)(src + 4);
            a[t][0] = (short)f2b(f0.x); a[t][1] = (short)f2b(f0.y);
            a[t][2] = (short)f2b(f0.z); a[t][3] = (short)f2b(f0.w);
            a[t][4] = (short)f2b(f1.x); a[t][5] = (short)f2b(f1.y);
            a[t][6] = (short)f2b(f1.z); a[t][7] = (short)f2b(f1.w);
        }
#pragma unroll
        for (int ct = 0; ct < 6; ++ct) {
            bf16x8 bb = *(const bf16x8*)&sB[((kt * 6 + ct) * 64 + lane) * 8];
            acc[0][ct] = __builtin_amdgcn_mfma_f32_16x16x32_bf16(a[0], bb, acc[0][ct], 0, 0, 0);
            acc[1][ct] = __builtin_amdgcn_mfma_f32_16x16x32_bf16(a[1], bb, acc[1][ct], 0, 0, 0);
        }
    }
    __syncthreads();
#pragma unroll
    for (int t = 0; t < 2; ++t)
#pragma unroll
        for (int ct = 0; ct < 6; ++ct) {
            int col = ct * 16 + (lane & 15);
            float bv = bias[col];
#pragma unroll
            for (int i = 0; i < 4; ++i) {
                int rb = rowb + t * 16 + (lane >> 4) * 4 + i;
                float v = acc[t][ct][i] + bv;
                sT[rb * HID + col] = f2b(v > 0.f ? v : 0.f);
            }
        }
    __syncthreads();
    for (int i = tid; i < 1536; i += 256) {
        int r = i / 12;
        int g = b * 128 + r;
        if (g < NN) ((uint4*)(h + (size_t)g * HID))[i % 12] = ((uint4*)sT)[i];
    }
}

// ---- fill3: self-scan bucket bases + per-bucket node hist/scan -> rp, col ----
__global__ __launch_bounds__(256) void k_fill3(const uint* __restrict__ part,
        const int* __restrict__ gcur, int* __restrict__ rp, int* __restrict__ col) {
    __shared__ int lh[512];
    __shared__ int lsc[512];
    __shared__ int pairs[256];
    __shared__ int sge[256];
    const int tid = threadIdx.x;
    const int bk = blockIdx.x;
    int gv = (tid < NBK2) ? gcur[tid] : 0;
    sge[tid] = gv;
    lh[tid] = 0; lh[tid + 256] = 0;
    __syncthreads();
    for (int off = 1; off < 256; off <<= 1) {
        int t = (tid >= off) ? sge[tid - off] : 0;
        __syncthreads();
        sge[tid] += t;
        __syncthreads();
    }
    int incl = sge[tid];
    __syncthreads();
    sge[tid] = incl - gv;          // exclusive
    __syncthreads();
    const int base = sge[bk];
    const int cnt = gcur[bk];
    const uint* pb = part + (size_t)bk * BCAP;
    for (int e = tid; e < cnt; e += 256) atomicAdd(&lh[pb[e] >> 17], 1);
    __syncthreads();
    int p0 = lh[2 * tid], p1 = lh[2 * tid + 1];
    int ps = p0 + p1;
    pairs[tid] = ps;
    __syncthreads();
    for (int off = 1; off < 256; off <<= 1) {
        int t = (tid >= off) ? pairs[tid - off] : 0;
        __syncthreads();
        pairs[tid] += t;
        __syncthreads();
    }
    int excl = base + pairs[tid] - ps;
    lsc[2 * tid] = excl;
    lsc[2 * tid + 1] = excl + p0;
    __syncthreads();
    const int n0 = bk * 512;
    for (int i = tid; i < 512; i += 256) {
        int n = n0 + i;
        if (n < NN) rp[n] = lsc[i];
    }
    if (bk == NBK2 - 1 && tid == 0) rp[NN] = NE;
    __syncthreads();
    for (int e = tid; e < cnt; e += 256) {
        uint v = pb[e];
        int pos = atomicAdd(&lsc[v >> 17], 1);
        col[pos] = (int)(v & 0x1FFFF);
    }
}

// ---- mean aggregation: 16 lanes/node, 4-edge unroll, BN(prev)+ReLU fused ----
__global__ __launch_bounds__(256, 8) void k_agg(const ushort* __restrict__ pre,
        const int* __restrict__ rp, const int* __restrict__ col,
        const float* __restrict__ stats, const float* __restrict__ gamma,
        const float* __restrict__ beta, ushort* __restrict__ agg) {
    __shared__ float sc[96], sh[96];
    const int tid = threadIdx.x;
    if (tid < 96) {
        float scv = 1.f, shv = 0.f;
        if (stats) {
            float mean = stats[tid] * (1.f / NN);
            float var  = stats[96 + tid] * (1.f / NN) - mean * mean;
            float s = gamma[tid] * rsqrtf(var + BN_EPS);
            scv = s; shv = beta[tid] - mean * s;
        }
        sc[tid] = scv; sh[tid] = shv;
    }
    __syncthreads();
    const int lane = tid & 15;
    const int n = blockIdx.x * 16 + (tid >> 4);
    if (n >= NN) return;
    const float s0a = sc[2*lane],      h0a = sh[2*lane];
    const float s0b = sc[2*lane + 1],  h0b = sh[2*lane + 1];
    const float s1a = sc[2*lane + 32], h1a = sh[2*lane + 32];
    const float s1b = sc[2*lane + 33], h1b = sh[2*lane + 33];
    const float s2a = sc[2*lane + 64], h2a = sh[2*lane + 64];
    const float s2b = sc[2*lane + 65], h2b = sh[2*lane + 65];
    const int e0 = rp[n], e1 = rp[n + 1];
    float a0 = 0.f, a1 = 0.f, a2 = 0.f, a3 = 0.f, a4 = 0.f, a5 = 0.f;
    const uint* hb = (const uint*)pre + lane;
    int e = e0;
    for (; e + 4 <= e1; e += 4) {
        uint u[4][3];
#pragma unroll
        for (int i = 0; i < 4; ++i) {
            const uint* r = hb + (size_t)col[e + i] * 48;
            u[i][0] = r[0]; u[i][1] = r[16]; u[i][2] = r[32];
        }
#pragma unroll
        for (int i = 0; i < 4; ++i) {
            a0 += fmaxf(b2f((ushort)u[i][0])         * s0a + h0a, 0.f);
            a1 += fmaxf(b2f((ushort)(u[i][0] >> 16)) * s0b + h0b, 0.f);
            a2 += fmaxf(b2f((ushort)u[i][1])         * s1a + h1a, 0.f);
            a3 += fmaxf(b2f((ushort)(u[i][1] >> 16)) * s1b + h1b, 0.f);
            a4 += fmaxf(b2f((ushort)u[i][2])         * s2a + h2a, 0.f);
            a5 += fmaxf(b2f((ushort)(u[i][2] >> 16)) * s2b + h2b, 0.f);
        }
    }
    for (; e < e1; ++e) {
        const uint* r = hb + (size_t)col[e] * 48;
        uint u0 = r[0], u1 = r[16], u2 = r[32];
        a0 += fmaxf(b2f((ushort)u0)         * s0a + h0a, 0.f);
        a1 += fmaxf(b2f((ushort)(u0 >> 16)) * s0b + h0b, 0.f);
        a2 += fmaxf(b2f((ushort)u1)         * s1a + h1a, 0.f);
        a3 += fmaxf(b2f((ushort)(u1 >> 16)) * s1b + h1b, 0.f);
        a4 += fmaxf(b2f((ushort)u2)         * s2a + h2a, 0.f);
        a5 += fmaxf(b2f((ushort)(u2 >> 16)) * s2b + h2b, 0.f);
    }
    int d = e1 - e0; if (d < 1) d = 1;
    float inv = 1.0f / (float)d;
    uint* ar = (uint*)agg + (size_t)n * 48 + lane;
    ar[0]  = pack2(a0 * inv, a1 * inv);
    ar[16] = pack2(a2 * inv, a3 * inv);
    ar[32] = pack2(a4 * inv, a5 * inv);
}

// ---- layer GEMM: hnew = [agg | norm_prev(pre)] @ [[wl],[wr]] + bl, fused BN stats ----
__global__ __launch_bounds__(256, 4) void k_gemm(const ushort* __restrict__ aggb,
        const ushort* __restrict__ pre, const ushort* __restrict__ Bf,
        const float* __restrict__ bl, ushort* __restrict__ hnew,
        float* __restrict__ stats,
        const float* __restrict__ statsP, const float* __restrict__ gammaP,
        const float* __restrict__ betaP) {
    __shared__ __align__(16) char smem[40704];
    ushort* sB = (ushort*)smem;
    ushort* sT = (ushort*)smem;
    float*  sredS = (float*)(smem + 36864);
    float*  sredQ = (float*)(smem + 38400);
    float2* sscsh = (float2*)(smem + 39936);
    const int tid = threadIdx.x;
    for (int i = tid; i < 2304; i += 256) ((uint4*)sB)[i] = ((const uint4*)Bf)[i];
    if (tid < 96) {
        float scv = 1.f, shv = 0.f;
        if (statsP) {
            float mean = statsP[tid] * (1.f / NN);
            float var  = statsP[96 + tid] * (1.f / NN) - mean * mean;
            float s = gammaP[tid] * rsqrtf(var + BN_EPS);
            scv = s; shv = betaP[tid] - mean * s;
        }
        sscsh[tid] = make_float2(scv, shv);
    }
    __syncthreads();
    const int wave = tid >> 6, lane = tid & 63;
    const int rowb = wave * 32;
    const int row0 = blockIdx.x * 128 + rowb;
    const int kof = (lane >> 4) * 8;
    f32x4 acc[2][6];
#pragma unroll
    for (int t = 0; t < 2; ++t)
#pragma unroll
        for (int c = 0; c < 6; ++c) acc[t][c] = (f32x4){0.f, 0.f, 0.f, 0.f};
#pragma unroll
    for (int kt = 0; kt < 6; ++kt) {
        bf16x8 a[2];
#pragma unroll
        for (int t = 0; t < 2; ++t) {
            int r = row0 + t * 16 + (lane & 15);
            if (r >= NN) r = NN - 1;
            if (kt < 3) {
                int kk = kt * 32 + kof;
                a[t] = *(const bf16x8*)(aggb + (size_t)r * HID + kk);
            } else {
                int kk = (kt - 3) * 32 + kof;
                bf16x8 raw = *(const bf16x8*)(pre + (size_t)r * HID + kk);
                union { bf16x8 h; uint u[4]; } pk;
#pragma unroll
                for (int j = 0; j < 4; ++j) {
                    float2 p0 = sscsh[kk + 2*j];
                    float2 p1 = sscsh[kk + 2*j + 1];
                    float v0 = fmaxf(b2f((ushort)raw[2*j])     * p0.x + p0.y, 0.f);
                    float v1 = fmaxf(b2f((ushort)raw[2*j + 1]) * p1.x + p1.y, 0.f);
                    pk.u[j] = pack2(v0, v1);
                }
                a[t] = pk.h;
            }
        }
#pragma unroll
        for (int ct = 0; ct < 6; ++ct) {
            bf16x8 bb = *(const bf16x8*)&sB[((kt * 6 + ct) * 64 + lane) * 8];
            acc[0][ct] = __builtin_amdgcn_mfma_f32_16x16x32_bf16(a[0], bb, acc[0][ct], 0, 0, 0);
            acc[1][ct] = __builtin_amdgcn_mfma_f32_16x16x32_bf16(a[1], bb, acc[1][ct], 0, 0, 0);
        }
    }
    __syncthreads();
    float s[6], q[6];
#pragma unroll
    for (int c = 0; c < 6; ++c) { s[c] = 0.f; q[c] = 0.f; }
#pragma unroll
    for (int t = 0; t < 2; ++t)
#pragma unroll
        for (int ct = 0; ct < 6; ++ct) {
            int col = ct * 16 + (lane & 15);
            float bv = bl[col];
#pragma unroll
            for (int i = 0; i < 4; ++i) {
                int rb = rowb + t * 16 + (lane >> 4) * 4 + i;
                int g = blockIdx.x * 128 + rb;
                float v = acc[t][ct][i] + bv;
                if (g < NN) { s[ct] += v; q[ct] += v * v; }
                sT[rb * HID + col] = f2b(v);
            }
        }
#pragma unroll
    for (int c = 0; c < 6; ++c) {
        s[c] += __shfl_xor(s[c], 16); s[c] += __shfl_xor(s[c], 32);
        q[c] += __shfl_xor(q[c], 16); q[c] += __shfl_xor(q[c], 32);
    }
    if (lane < 16) {
#pragma unroll
        for (int c = 0; c < 6; ++c) {
            sredS[wave * 96 + c * 16 + lane] = s[c];
            sredQ[wave * 96 + c * 16 + lane] = q[c];
        }
    }
    __syncthreads();
    if (tid < 96) {
        float S = sredS[tid] + sredS[96 + tid] + sredS[192 + tid] + sredS[288 + tid];
        float Q = sredQ[tid] + sredQ[96 + tid] + sredQ[192 + tid] + sredQ[288 + tid];
        atomicAdd(&stats[tid], S);
        atomicAdd(&stats[96 + tid], Q);
    }
    for (int i = tid; i < 1536; i += 256) {
        int r = i / 12;
        int g = blockIdx.x * 128 + r;
        if (g < NN) ((uint4*)(hnew + (size_t)g * HID))[i % 12] = ((uint4*)sT)[i];
    }
}

// ---------------- central-node MLP head (final BN+ReLU fused) ----------------
__global__ __launch_bounds__(128) void k_mlp(const ushort* __restrict__ pre,
        const int* __restrict__ cidx, const float* __restrict__ stats,
        const float* __restrict__ gamma, const float* __restrict__ beta,
        const float* __restrict__ W1, const float* __restrict__ b1,
        const float* __restrict__ W2, const float* __restrict__ b2,
        float* __restrict__ out) {
    __shared__ float nh[96];
    __shared__ float hid[96];
    __shared__ float red[128];
    const int c = blockIdx.x;
    const int node = cidx[c];
    const int tid = threadIdx.x;
    if (tid < 96) {
        float mean = stats[tid] * (1.f / NN);
        float var  = stats[96 + tid] * (1.f / NN) - mean * mean;
        float s = gamma[tid] * rsqrtf(var + BN_EPS);
        float v = b2f(pre[(size_t)node * 96 + tid]) * s + (beta[tid] - mean * s);
        nh[tid] = fmaxf(v, 0.f);
    }
    __syncthreads();
    if (tid < 96) {
        float a = 0.f;
        for (int k = 0; k < 96; ++k) a += nh[k] * W1[k * 96 + tid];
        hid[tid] = fmaxf(a + b1[tid], 0.f);
    }
    __syncthreads();
    red[tid] = (tid < 96) ? hid[tid] * W2[tid] : 0.f;
    __syncthreads();
    for (int off = 64; off > 0; off >>= 1) {
        if (tid < off) red[tid] += red[tid + off];
        __syncthreads();
    }
    if (tid == 0) out[c] = red[0] + b2[0];
}

extern "C" void kernel_launch(void* const* d_in, const int* in_sizes, int n_in,
                              void* d_out, int out_size, void* d_ws, size_t ws_size,
                              hipStream_t stream) {
    const float* x        = (const float*)d_in[0];
    const int*   ei       = (const int*)d_in[1];
    const int*   cidx     = (const int*)d_in[3];
    const float* W_emb    = (const float*)d_in[4];
    const float* b_emb    = (const float*)d_in[5];
    const float* conv_wl  = (const float*)d_in[6];
    const float* conv_bl  = (const float*)d_in[7];
    const float* conv_wr  = (const float*)d_in[8];
    const float* bn_gamma = (const float*)d_in[9];
    const float* bn_beta  = (const float*)d_in[10];
    const float* W1       = (const float*)d_in[11];
    const float* b1       = (const float*)d_in[12];
    const float* W2       = (const float*)d_in[13];
    const float* b2       = (const float*)d_in[14];
    float* out = (float*)d_out;

    char* ws = (char*)d_ws;
    size_t off = 0;
    auto alloc = [&](size_t bytes) -> void* {
        void* p = ws + off;
        off = (off + bytes + 255) & ~(size_t)255;
        return p;
    };
    ushort* h    = (ushort*)alloc((size_t)NN * 96 * 2);
    ushort* hnew = (ushort*)alloc((size_t)NN * 96 * 2);
    ushort* agg  = (ushort*)alloc((size_t)NN * 96 * 2);
    int*   gcur  = (int*)alloc(256 * 4);
    int*   rp    = (int*)alloc((size_t)(NN + 1) * 4);
    int*   col   = (int*)alloc((size_t)NE * 4);
    uint*  part  = (uint*)alloc((size_t)NBK2 * BCAP * 4);
    float* stats = (float*)alloc((size_t)NL * 192 * 4);
    ushort* Bfl  = (ushort*)alloc((size_t)NL * 6 * 6 * 64 * 8 * 2);
    (void)ws_size; (void)in_sizes; (void)n_in; (void)out_size;

    hipMemsetAsync(gcur, 0, 256 * 4, stream);

    k_front<<<NBE + NBP + NBF, 256, 0, stream>>>(x, W_emb, b_emb, h,
        conv_wl, conv_wr, Bfl, stats, ei, gcur, part);
    k_fill3<<<NBK2, 256, 0, stream>>>(part, gcur, rp, col);

    // ping-pong: src -> dst per layer
    const ushort* src = h;
    ushort* dst = hnew;
    for (int l = 0; l < NL; ++l) {
        const float* stP = (l == 0) ? nullptr : stats + (size_t)(l - 1) * 192;
        const float* gP  = (l == 0) ? nullptr : bn_gamma + (size_t)(l - 1) * 96;
        const float* bP  = (l == 0) ? nullptr : bn_beta + (size_t)(l - 1) * 96;
        k_agg<<<(NN + 15) / 16, 256, 0, stream>>>(src, rp, col, stP, gP, bP, agg);
        k_gemm<<<(NN + 127) / 128, 256, 0, stream>>>(agg, src,
            Bfl + (size_t)l * 18432, conv_bl + (size_t)l * 96, dst,
            stats + (size_t)l * 192, stP, gP, bP);
        const ushort* t = src; src = dst; dst = (ushort*)t;
    }
    k_mlp<<<NC, 128, 0, stream>>>(src, cidx, stats + (size_t)(NL - 1) * 192,
        bn_gamma + (size_t)(NL - 1) * 96, bn_beta + (size_t)(NL - 1) * 96,
        W1, b1, W2, b2, out);
}